// Round 9
// baseline (169.639 us; speedup 1.0000x reference)
//
#include <hip/hip_runtime.h>
#include <math.h>

#define BS   8
#define NPTS 2048
#define CCH  12      // channels per flow
#define NF   2       // flow dim
#define DIM  24      // NF*CCH, feats order: d = f*12 + c
#define KTOP 16
#define NWV  16      // waves per fused block (1024 threads)
#define CPW  (NPTS / NWV)   // 128 candidates per wave
#define CBUF 33      // collected-candidate buffer slots per row (padded: 33*8B breaks bank alias)

#define NROWS    (BS * NPTS)
#define TGT_BASE (NROWS * KTOP * CCH)   // 3145728

typedef unsigned long long u64;
typedef unsigned int       u32;

// ws layout (bytes): feats [NROWS][DIM] | raw [NROWS][CCH]
#define WS_FEATS 0
#define WS_RAW   (NROWS * DIM * 4)                 // 1572864

// Emulate np.linalg.norm(v) + 1e-8 in float32 exactly (numpy pairwise sum, n=24):
//   r[j] = (s[j] + s[j+8]) + s[j+16];  res = ((r0+r1)+(r2+r3)) + ((r4+r5)+(r6+r7))
__device__ __forceinline__ float np_norm_den(const float* __restrict__ v)
{
#pragma clang fp contract(off)
    float s[DIM];
    #pragma unroll
    for (int d = 0; d < DIM; ++d) s[d] = v[d] * v[d];
    float r[8];
    #pragma unroll
    for (int j = 0; j < 8; ++j) r[j] = (s[j] + s[j + 8]) + s[j + 16];
    float res = ((r[0] + r[1]) + (r[2] + r[3])) + ((r[4] + r[5]) + (r[6] + r[7]));
    return sqrtf(res) + 1e-8f;
}

// Monotone float -> u32 (preserves total order for finite floats)
__device__ __forceinline__ u32 ordf(float f)
{
    u32 u = __float_as_uint(f);
    return ((int)u >= 0) ? (u | 0x80000000u) : ~u;
}

// ---------------------------------------------------------------------------
// Kernel 0: normalize every row (numpy-exact fp32), write contiguous feats,
// raw flow-slice (gather-friendly), and the tgt_out output.  (unchanged)
// ---------------------------------------------------------------------------
__global__ __launch_bounds__(256) void prep_kernel(
    const float* __restrict__ x_c,     // [8][12][2][2048]
    const int*   __restrict__ flow_p,
    float*       __restrict__ feats,   // [NROWS][DIM] normalized
    float*       __restrict__ raw,     // [NROWS][CCH] raw flow slice
    float*       __restrict__ out)
{
    const int t = blockIdx.x * 256 + threadIdx.x;   // global row
    const int b = t >> 11;
    const int n = t & (NPTS - 1);
    const float* xb = x_c + (size_t)b * CCH * NF * NPTS;

    float v[DIM];
    {
#pragma clang fp contract(off)
        #pragma unroll
        for (int c = 0; c < CCH; ++c)
            #pragma unroll
            for (int f = 0; f < NF; ++f)
                v[f * CCH + c] = xb[(c * NF + f) * NPTS + n];

        const float den = np_norm_den(v);
        float* fo = feats + (size_t)t * DIM;
        #pragma unroll
        for (int d = 0; d < DIM; ++d) fo[d] = v[d] / den;
    }

    const int flow = flow_p[0];
    float* ro = raw + (size_t)t * CCH;
    #pragma unroll
    for (int c = 0; c < CCH; ++c) {
        const float xv = flow ? v[CCH + c] : v[c];   // raw value, pre-norm
        ro[c] = xv;
        out[TGT_BASE + ((size_t)b * CCH + c) * NPTS + n] = xv;   // tgt_out
    }
}

// ---------------------------------------------------------------------------
// Fused kernel: block = (b, 64-row chunk), 1024 thr = 16 waves; lane = row.
// Pass 1 (values only, f32 min/max CEs): wave w scans cands [w*128,+128),
// keeps per-row top-16 VALUES via batch-16 bitonic; per-row 16-way merge of
// wave lists yields v16 = exact 16th-largest value.
// Pass 2: recompute dots (bit-identical FMA chain), collect all cands with
// acc >= v16 (u64 key = ordf(val)<<32 | (2047-idx)) into LDS via atomic cnt.
// Final: per-row top-16 of collected keys (exact desc/value, asc/index),
// then in-block gather of sx_c from raw.
// ---------------------------------------------------------------------------
__global__ __launch_bounds__(1024) void fused_topk_kernel(
    const float* __restrict__ feats,
    const float* __restrict__ raw,
    float*       __restrict__ out)
{
    __shared__ float vkeys[NWV][KTOP][64];   // 64 KiB: per-wave sorted value lists
    __shared__ u64   cbuf[64][CBUF];         // 16.5 KiB: collected (val,idx) keys
    __shared__ float v16s[64];
    __shared__ int   cnt[64];
    __shared__ int   sel[64][KTOP];          // 4 KiB

    const int tid  = threadIdx.x;
    const int lane = tid & 63;
    const int w    = __builtin_amdgcn_readfirstlane(tid >> 6);  // uniform wave id
    const int b     = blockIdx.x >> 5;
    const int chunk = blockIdx.x & 31;
    const int row   = b * NPTS + chunk * 64 + lane;

    if (tid < 64) cnt[tid] = 0;

    // own row's normalized vector (per-lane)
    float rfn[DIM];
    {
        const float* fr = feats + (size_t)row * DIM;
        #pragma unroll
        for (int d = 0; d < DIM; ++d) rfn[d] = fr[d];
    }

    const int    mg0 = w * CPW;
    const float* cb  = feats + ((size_t)b * NPTS + mg0) * DIM;  // uniform base

    // ---- Pass 1: top-16 VALUES (sorted desc), f32 CEs ----
    float vlist[KTOP];
    #pragma unroll
    for (int k = 0; k < KTOP; ++k) vlist[k] = -3.0f;   // < any cosine

    for (int jb = 0; jb < CPW; jb += 16) {
        float bv[16];
        #pragma unroll 4
        for (int jj = 0; jj < 16; ++jj) {
            const float* cp = cb + (size_t)(jb + jj) * DIM;   // wave-uniform
            float acc = 0.0f;
            #pragma unroll
            for (int d = 0; d < DIM; ++d)
                acc = __builtin_fmaf(cp[d], rfn[d], acc);     // exact chain
            bv[jj] = acc;
        }
        // bitonic sort 16 ASCENDING (min/max CEs)
        #pragma unroll
        for (int k = 2; k <= 16; k <<= 1)
            #pragma unroll
            for (int j = k >> 1; j > 0; j >>= 1)
                #pragma unroll
                for (int i = 0; i < 16; ++i) {
                    const int l = i | j;
                    if (l > i) {
                        const float a = bv[i], c = bv[l];
                        if ((i & k) == 0) { bv[i] = fminf(a, c); bv[l] = fmaxf(a, c); }
                        else              { bv[i] = fmaxf(a, c); bv[l] = fminf(a, c); }
                    }
                }
        // merge (list desc + batch asc -> bitonic), then cleanup desc
        #pragma unroll
        for (int i = 0; i < 16; ++i) vlist[i] = fmaxf(vlist[i], bv[i]);
        #pragma unroll
        for (int j = 8; j > 0; j >>= 1)
            #pragma unroll
            for (int i = 0; i < 16; ++i) {
                const int l = i | j;
                if (l > i) {
                    const float a = vlist[i], c = vlist[l];
                    vlist[i] = fmaxf(a, c);
                    vlist[l] = fminf(a, c);
                }
            }
    }

    #pragma unroll
    for (int k = 0; k < KTOP; ++k) vkeys[w][k][lane] = vlist[k];
    __syncthreads();

    // ---- v16: 16-way merge of sorted value lists, take the 16th ----
    if (tid < 64) {
        int h[NWV];
        #pragma unroll
        for (int j = 0; j < NWV; ++j) h[j] = 0;
        float last = -4.0f;
        for (int k = 0; k < KTOP; ++k) {
            float best = -4.0f; int bj = 0;
            #pragma unroll
            for (int j = 0; j < NWV; ++j) {
                const float v = vkeys[j][h[j]][tid];
                if (v > best) { best = v; bj = j; }
            }
            h[bj]++;
            last = best;
        }
        v16s[tid] = last;
    }
    __syncthreads();

    const float v16 = v16s[lane];

    // ---- Pass 2: recompute dots (identical chain), collect acc >= v16 ----
    #pragma unroll 4
    for (int j = 0; j < CPW; ++j) {
        const float* cp = cb + (size_t)j * DIM;   // wave-uniform
        float acc = 0.0f;
        #pragma unroll
        for (int d = 0; d < DIM; ++d)
            acc = __builtin_fmaf(cp[d], rfn[d], acc);         // exact chain
        if (acc >= v16) {
            const int p = atomicAdd(&cnt[lane], 1);
            if (p < CBUF)
                cbuf[lane][p] = ((u64)ordf(acc) << 32) | (u32)(2047 - (mg0 + j));
        }
    }
    __syncthreads();

    // ---- final per-row top-16 of collected keys ----
    if (tid < 64) {
        const int e = (cnt[tid] < CBUF) ? cnt[tid] : CBUF;
        for (int k = 0; k < KTOP; ++k) {
            u64 best = 0; int bp = 0;
            for (int p = 0; p < e; ++p) {
                const u64 v = cbuf[tid][p];
                if (v > best) { best = v; bp = p; }
            }
            cbuf[tid][bp] = 0;
            sel[tid][k] = 2047 - (int)(best & 0xFFFFFFFFull);
        }
    }
    __syncthreads();

    // ---- gather: sx_c[b, n, k, c] = raw[(b*2048 + sel)*12 + c] ----
    const int rb = b * NPTS + chunk * 64;
    for (int e = tid; e < 64 * KTOP * CCH; e += 1024) {
        const int L = e / (KTOP * CCH);
        const int r = e % (KTOP * CCH);
        const int k = r / CCH;
        const int c = r % CCH;
        out[((size_t)(rb + L) * KTOP + k) * CCH + c] =
            raw[((size_t)b * NPTS + sel[L][k]) * CCH + c];
    }
}

// ---------------------------------------------------------------------------
extern "C" void kernel_launch(void* const* d_in, const int* in_sizes, int n_in,
                              void* d_out, int out_size, void* d_ws, size_t ws_size,
                              hipStream_t stream)
{
    const float* x_c    = (const float*)d_in[0];
    const int*   flow_p = (const int*)d_in[1];
    float*       out    = (float*)d_out;

    float* feats = (float*)((char*)d_ws + WS_FEATS);
    float* raw   = (float*)((char*)d_ws + WS_RAW);

    prep_kernel<<<NROWS / 256, 256, 0, stream>>>(x_c, flow_p, feats, raw, out);
    fused_topk_kernel<<<BS * 32, 1024, 0, stream>>>(feats, raw, out);
}